// Round 9
// baseline (765.487 us; speedup 1.0000x reference)
//
#include <hip/hip_runtime.h>
#include <hip/hip_bf16.h>

// SupPixPool: out[b,c,k] = max over pixels p with spx[b,p]==k of img[b,c,p].
// B=4, C=64, H=W=512, K=1024.
//
// Round-9: single fused kernel. R6 core (wave-per-channel 1KB contiguous NT
// loads, register pipeline, stride-9 padded LDS table, unconditional ds_max)
// + fan-in finale replacing the separate reduce kernel: each block dumps its
// partial to ws, release-stores flag[bx]=0x5EC70000^bx (agent scope), then
// thread0 acquire-loads its tile's 16 flags; blocks seeing all 16 reduce the
// tile (idempotent; >=1 winner guaranteed - the real-time-last block sees all;
// duplicates write identical values). Poison-independent: winner requires 16
// exact 32-bit magics. Saves one kernel node + inter-node gap (~10-15us).

constexpr int Kseg = 1024;
constexpr int Bn   = 4;
constexpr int Cn   = 64;
constexpr int HWn  = 512 * 512;

constexpr int CH     = 8;             // channels per block
constexpr int NCG    = Cn / CH;       // 8
constexpr int TPB    = 1024;          // 16 waves
constexpr int NCHUNK = 16;            // pixel chunks per (b, cg)
constexpr int PIX    = HWn / NCHUNK;  // 16384 pixels per block
constexpr int STR    = 9;             // padded table stride (36 KB)
constexpr int TBLW   = Kseg * STR;    // 9216 words
constexpr int PARTW  = Kseg * CH;     // 8192 words dumped (unpadded)
constexpr int NBLK   = Bn * NCG * NCHUNK;  // 512
constexpr int ITERS  = 16;            // 2 quads/lane/iter, 256 quads/iter/ch

typedef float  vf4 __attribute__((ext_vector_type(4)));
typedef int    vi4 __attribute__((ext_vector_type(4)));

// order-preserving float->uint encoding: enc monotonic, unsigned max == fmax
constexpr unsigned ENEG = 0x007FFFFFu;  // enc(-inf)

__device__ __forceinline__ unsigned enc(float f) {
    unsigned u = __float_as_uint(f);
    return u ^ ((unsigned)((int)u >> 31) | 0x80000000u);
}
__device__ __forceinline__ float dec(unsigned e) {
    unsigned u = (e & 0x80000000u) ? (e ^ 0x80000000u) : ~e;
    return __uint_as_float(u);
}

__device__ __forceinline__ unsigned magic(int bx) {
    return 0x5EC70000u ^ (unsigned)bx;
}

__global__ __launch_bounds__(TPB, 8) void pool_fused(
    const float* __restrict__ img, const int* __restrict__ spx,
    unsigned* __restrict__ part, unsigned* __restrict__ flags,
    float* __restrict__ out) {
    __shared__ unsigned tbl[TBLW];  // 36 KB, [k][9] padded
    __shared__ unsigned s_win;

    const int bx    = blockIdx.x;
    const int chunk = bx % NCHUNK;
    const int cg    = (bx / NCHUNK) % NCG;
    const int b     = bx / (NCHUNK * NCG);

    for (int i = threadIdx.x; i < TBLW; i += TPB) tbl[i] = ENEG;
    __syncthreads();

    const int wave = threadIdx.x >> 6;
    const int lane = threadIdx.x & 63;
    const int c    = wave & (CH - 1);   // channel owned by this wave
    const int h    = wave >> 3;         // half of each 256-quad stripe pair

    const float* imgc = img + ((size_t)(b * Cn + cg * CH + c)) * HWn
                            + (size_t)chunk * PIX;
    const int*   spxb = spx + (size_t)b * HWn + (size_t)chunk * PIX;

    const int q0 = h * 64 + lane;  // base quad; +256 per iteration, pair +128

    // depth-1 pipeline over a 2-quad body: 4 loads in flight
    vf4 va = __builtin_nontemporal_load((const vf4*)(imgc + 4 * q0));
    vi4 ka = *(const vi4*)(spxb + 4 * q0);
    vf4 vb = __builtin_nontemporal_load((const vf4*)(imgc + 4 * (q0 + 128)));
    vi4 kb = *(const vi4*)(spxb + 4 * (q0 + 128));

#pragma unroll 4
    for (int it = 0; it < ITERS; ++it) {
        vf4 van, vbn;
        vi4 kan, kbn;
        if (it + 1 < ITERS) {
            const int qn = q0 + (it + 1) * 256;
            van = __builtin_nontemporal_load((const vf4*)(imgc + 4 * qn));
            kan = *(const vi4*)(spxb + 4 * qn);
            vbn = __builtin_nontemporal_load((const vf4*)(imgc + 4 * (qn + 128)));
            kbn = *(const vi4*)(spxb + 4 * (qn + 128));
        }
        atomicMax(tbl + ((ka.x & (Kseg - 1)) * STR + c), enc(va.x));
        atomicMax(tbl + ((ka.y & (Kseg - 1)) * STR + c), enc(va.y));
        atomicMax(tbl + ((ka.z & (Kseg - 1)) * STR + c), enc(va.z));
        atomicMax(tbl + ((ka.w & (Kseg - 1)) * STR + c), enc(va.w));
        atomicMax(tbl + ((kb.x & (Kseg - 1)) * STR + c), enc(vb.x));
        atomicMax(tbl + ((kb.y & (Kseg - 1)) * STR + c), enc(vb.y));
        atomicMax(tbl + ((kb.z & (Kseg - 1)) * STR + c), enc(vb.z));
        atomicMax(tbl + ((kb.w & (Kseg - 1)) * STR + c), enc(vb.w));
        va = van; ka = kan; vb = vbn; kb = kbn;
    }
    __syncthreads();

    // dump unpadded: entry index i = k*CH + j  <-  tbl[k*STR + j]
    unsigned* dst = part + (size_t)bx * PARTW;
    for (int i = threadIdx.x; i < PARTW; i += TPB) {
        const int k = i >> 3, j = i & (CH - 1);
        dst[i] = tbl[k * STR + j];
    }

    // publish + fan-in election
    __threadfence();
    __syncthreads();
    if (threadIdx.x == 0) {
        __hip_atomic_store(flags + bx, magic(bx), __ATOMIC_RELEASE,
                           __HIP_MEMORY_SCOPE_AGENT);
        const int base = (bx / NCHUNK) * NCHUNK;
        unsigned ok = 1;
        for (int ch = 0; ch < NCHUNK; ++ch) {
            unsigned f = __hip_atomic_load(flags + base + ch, __ATOMIC_ACQUIRE,
                                           __HIP_MEMORY_SCOPE_AGENT);
            ok &= (f == magic(base + ch));
        }
        s_win = ok;
    }
    __syncthreads();
    if (!s_win) return;

    // winner: reduce this (b,cg) tile's 16 partials. thread t owns k=t, all j.
    const unsigned* pbase = part + (size_t)(bx / NCHUNK) * NCHUNK * PARTW;
    const int t = threadIdx.x;  // == k (PARTW/CH == TPB)
    unsigned acc[CH];
#pragma unroll
    for (int j = 0; j < CH; ++j) acc[j] = ENEG;
    for (int ch = 0; ch < NCHUNK; ++ch) {
        const unsigned* row = pbase + (size_t)ch * PARTW + t * CH;
#pragma unroll
        for (int j = 0; j < CH; ++j) {
            unsigned e = __hip_atomic_load(row + j, __ATOMIC_RELAXED,
                                           __HIP_MEMORY_SCOPE_AGENT);
            acc[j] = max(acc[j], e);
        }
    }
    float* outb = out + ((size_t)b * Cn + cg * CH) * Kseg;
#pragma unroll
    for (int j = 0; j < CH; ++j)
        outb[(size_t)j * Kseg + t] = dec(acc[j]);
}

// -------- fallback path (ws too small): global atomic merge into d_out -----
__global__ __launch_bounds__(256) void init_enc_k(unsigned* __restrict__ o) {
    o[blockIdx.x * 256 + threadIdx.x] = ENEG;
}

__global__ __launch_bounds__(TPB, 8) void pool_atomic(
    const float* __restrict__ img, const int* __restrict__ spx,
    unsigned* __restrict__ gtab) {
    __shared__ unsigned tbl[TBLW];

    const int bx    = blockIdx.x;
    const int chunk = bx % NCHUNK;
    const int cg    = (bx / NCHUNK) % NCG;
    const int b     = bx / (NCHUNK * NCG);

    for (int i = threadIdx.x; i < TBLW; i += TPB) tbl[i] = ENEG;
    __syncthreads();

    const int wave = threadIdx.x >> 6;
    const int lane = threadIdx.x & 63;
    const int c    = wave & (CH - 1);
    const int h    = wave >> 3;

    const float* imgc = img + ((size_t)(b * Cn + cg * CH + c)) * HWn
                            + (size_t)chunk * PIX;
    const int*   spxb = spx + (size_t)b * HWn + (size_t)chunk * PIX;

    const int q0 = h * 64 + lane;

#pragma unroll 4
    for (int it = 0; it < ITERS; ++it) {
        const int qa = q0 + it * 256;
        const vf4 va = *(const vf4*)(imgc + 4 * qa);
        vi4 ka = *(const vi4*)(spxb + 4 * qa);
        const vf4 vb = *(const vf4*)(imgc + 4 * (qa + 128));
        vi4 kb = *(const vi4*)(spxb + 4 * (qa + 128));
        atomicMax(tbl + ((ka.x & (Kseg - 1)) * STR + c), enc(va.x));
        atomicMax(tbl + ((ka.y & (Kseg - 1)) * STR + c), enc(va.y));
        atomicMax(tbl + ((ka.z & (Kseg - 1)) * STR + c), enc(va.z));
        atomicMax(tbl + ((ka.w & (Kseg - 1)) * STR + c), enc(va.w));
        atomicMax(tbl + ((kb.x & (Kseg - 1)) * STR + c), enc(vb.x));
        atomicMax(tbl + ((kb.y & (Kseg - 1)) * STR + c), enc(vb.y));
        atomicMax(tbl + ((kb.z & (Kseg - 1)) * STR + c), enc(vb.z));
        atomicMax(tbl + ((kb.w & (Kseg - 1)) * STR + c), enc(vb.w));
    }
    __syncthreads();

    unsigned* base = gtab + (size_t)(b * Cn + cg * CH) * Kseg;
    for (int i = threadIdx.x; i < Kseg * CH; i += TPB) {
        const int k = i >> 3, j = i & (CH - 1);
        atomicMax(base + (size_t)j * Kseg + k, tbl[k * STR + j]);
    }
}

__global__ __launch_bounds__(256) void decode_inplace(unsigned* __restrict__ o) {
    const int i = blockIdx.x * 256 + threadIdx.x;
    const unsigned e = o[i];
    ((float*)o)[i] = dec(e);
}

extern "C" void kernel_launch(void* const* d_in, const int* in_sizes, int n_in,
                              void* d_out, int out_size, void* d_ws, size_t ws_size,
                              hipStream_t stream) {
    const float* img = (const float*)d_in[0];
    const int*   spx = (const int*)d_in[1];
    float*       out = (float*)d_out;

    const size_t offw = (size_t)NBLK * PARTW;              // partials words
    const size_t need = (offw + NBLK) * sizeof(unsigned);  // + flags
    const int nOut256 = (Bn * Cn * Kseg) / 256;            // 1024

    if (ws_size >= need) {
        unsigned* part  = (unsigned*)d_ws;
        unsigned* flags = part + offw;
        pool_fused<<<NBLK, TPB, 0, stream>>>(img, spx, part, flags, out);
    } else {
        unsigned* gt = (unsigned*)d_out;
        init_enc_k<<<nOut256, 256, 0, stream>>>(gt);
        pool_atomic<<<NBLK, TPB, 0, stream>>>(img, spx, gt);
        decode_inplace<<<nOut256, 256, 0, stream>>>(gt);
    }
}